// Round 1
// baseline (4271.903 us; speedup 1.0000x reference)
//
#include <hip/hip_runtime.h>
#include <hip/hip_bf16.h>

using bf16 = __hip_bfloat16;

#define CB 2
#define CS 2048
#define CD 1024
#define CH 16
#define CKH 4
#define CHD 64
#define CREP 4
#define CNQ (CH*CHD)    // 1024
#define CNKV (CKH*CHD)  // 256
#define CM (CB*CS)      // 4096

__device__ __forceinline__ float bf2f(unsigned short u) {
  union { unsigned int i; float f; } c;
  c.i = ((unsigned int)u) << 16;
  return c.f;
}

// ---------------------------------------------------------------------------
// Generic fp32 tiled GEMM: C[M,N] = A[M,K] @ W[K,N], all row-major fp32.
// 64x64 tile, BK=16, 256 threads (16x16), 4x4 microtile per thread.
// M,N,K must be multiples of 64/64/16 (true for all four calls here).
// ---------------------------------------------------------------------------
__global__ __launch_bounds__(256) void gemm_f32_kernel(
    const float* __restrict__ A, const float* __restrict__ W,
    float* __restrict__ C, int Mm, int Nn, int Kk)
{
  __shared__ __align__(16) float As[16][68];  // [k][m], padded
  __shared__ __align__(16) float Ws[16][68];  // [k][n], padded
  const int tid = threadIdx.x;
  const int tx = tid & 15, ty = tid >> 4;
  const int mBase = blockIdx.x * 64;
  const int nBase = blockIdx.y * 64;
  float acc[4][4] = {{0.f}};
  for (int k0 = 0; k0 < Kk; k0 += 16) {
    #pragma unroll
    for (int it = 0; it < 4; ++it) {
      int e = tid + it * 256;
      int r = e >> 4, kk = e & 15;
      As[kk][r] = A[(size_t)(mBase + r) * Kk + (k0 + kk)];
      int kw = e >> 6, n = e & 63;
      Ws[kw][n] = W[(size_t)(k0 + kw) * Nn + (nBase + n)];
    }
    __syncthreads();
    #pragma unroll
    for (int kk = 0; kk < 16; ++kk) {
      float4 av = *(const float4*)&As[kk][ty * 4];
      float4 bv = *(const float4*)&Ws[kk][tx * 4];
      float a_[4] = {av.x, av.y, av.z, av.w};
      float b_[4] = {bv.x, bv.y, bv.z, bv.w};
      #pragma unroll
      for (int i = 0; i < 4; ++i)
        #pragma unroll
        for (int j = 0; j < 4; ++j)
          acc[i][j] = fmaf(a_[i], b_[j], acc[i][j]);
    }
    __syncthreads();
  }
  #pragma unroll
  for (int i = 0; i < 4; ++i) {
    float4 o = make_float4(acc[i][0], acc[i][1], acc[i][2], acc[i][3]);
    *(float4*)&C[(size_t)(mBase + ty * 4 + i) * Nn + nBase + tx * 4] = o;
  }
}

// ---------------------------------------------------------------------------
// RoPE on q: read q_f32 [B,S,H*HD], write bf16 [B,H,S,HD] with interleaved
// pair rotation. One thread per pair. total = B*S*H*32 = 2^21.
// ---------------------------------------------------------------------------
__global__ void rope_q_kernel(const float* __restrict__ qf,
                              const float* __restrict__ fc,
                              const float* __restrict__ fs,
                              bf16* __restrict__ qb)
{
  int p = blockIdx.x * blockDim.x + threadIdx.x;
  int j = p & 31;
  int h = (p >> 5) & 15;
  int s = (p >> 9) & 2047;
  int b = p >> 20;
  const float* src = qf + (size_t)(b * CS + s) * CNQ + h * CHD + j * 2;
  float x0 = src[0], x1 = src[1];
  float c = fc[s * 32 + j], sn = fs[s * 32 + j];
  bf16* dst = qb + ((size_t)(b * CH + h) * CS + s) * CHD + j * 2;
  dst[0] = __float2bfloat16(x0 * c - x1 * sn);
  dst[1] = __float2bfloat16(x0 * sn + x1 * c);
}

// RoPE on k: [B,S,KH*HD] f32 -> [B,KH,S,HD] bf16. total = B*S*KH*32 = 2^19.
__global__ void rope_k_kernel(const float* __restrict__ kf,
                              const float* __restrict__ fc,
                              const float* __restrict__ fs,
                              bf16* __restrict__ kb)
{
  int p = blockIdx.x * blockDim.x + threadIdx.x;
  int j = p & 31;
  int kh = (p >> 5) & 3;
  int s = (p >> 7) & 2047;
  int b = p >> 18;
  const float* src = kf + (size_t)(b * CS + s) * CNKV + kh * CHD + j * 2;
  float x0 = src[0], x1 = src[1];
  float c = fc[s * 32 + j], sn = fs[s * 32 + j];
  bf16* dst = kb + ((size_t)(b * CKH + kh) * CS + s) * CHD + j * 2;
  dst[0] = __float2bfloat16(x0 * c - x1 * sn);
  dst[1] = __float2bfloat16(x0 * sn + x1 * c);
}

// v: [B,S,KH*HD] f32 -> [B,KH,S,HD] bf16. total = B*S*KH*64 = 2^20.
__global__ void conv_v_kernel(const float* __restrict__ vf, bf16* __restrict__ vb)
{
  int e = blockIdx.x * blockDim.x + threadIdx.x;
  int d = e & 63;
  int kh = (e >> 6) & 3;
  int s = (e >> 8) & 2047;
  int b = e >> 19;
  vb[((size_t)(b * CKH + kh) * CS + s) * CHD + d] =
      __float2bfloat16(vf[(size_t)(b * CS + s) * CNKV + kh * CHD + d]);
}

// ---------------------------------------------------------------------------
// Flash attention: one wave per block, thread = one q row, 64-row q tile,
// 64-row K/V tiles staged to LDS as f32. Online softmax in f32, causal.
// Scores parked in padded LDS (avoids runtime-indexed register arrays).
// q: [B,H,S,HD] bf16; k,v: [B,KH,S,HD] bf16; out: [B,S,H*HD] f32.
// ---------------------------------------------------------------------------
__global__ __launch_bounds__(64) void flash_kernel(
    const bf16* __restrict__ qb, const bf16* __restrict__ kb,
    const bf16* __restrict__ vb, float* __restrict__ of)
{
  __shared__ __align__(16) float Ks[64][64];
  __shared__ __align__(16) float Vs[64][64];
  __shared__ __align__(16) float Ss[64][65];  // padded: bank = (tid+j)%32
  const int blk = blockIdx.x;
  const int qt = blk & 31;          // S/64 = 32
  const int h  = (blk >> 5) & 15;
  const int b  = blk >> 9;
  const int kh = h >> 2;            // REP = 4
  const int tid = threadIdx.x;
  const int qi = qt * 64 + tid;

  // q row -> f32 registers
  const bf16* qrow = qb + ((size_t)(b * CH + h) * CS + qi) * CHD;
  float q[64];
  #pragma unroll
  for (int v8 = 0; v8 < 8; ++v8) {
    union { uint4 u; unsigned short s[8]; } cv;
    cv.u = *(const uint4*)(qrow + v8 * 8);
    #pragma unroll
    for (int t = 0; t < 8; ++t) q[v8 * 8 + t] = bf2f(cv.s[t]);
  }
  const bf16* kbase = kb + (size_t)(b * CKH + kh) * CS * CHD;
  const bf16* vbase = vb + (size_t)(b * CKH + kh) * CS * CHD;

  float m = -1e30f, l = 0.f;
  float o[64];
  #pragma unroll
  for (int d = 0; d < 64; ++d) o[d] = 0.f;

  const int ntiles = qt + 1;  // causal: tiles 0..qt (uniform across block)
  for (int t = 0; t < ntiles; ++t) {
    __syncthreads();
    // stage K,V tile (64x64 bf16 each), coalesced 16B loads, f32 in LDS
    #pragma unroll
    for (int it = 0; it < 8; ++it) {
      int f8 = it * 64 + tid;
      int row = f8 >> 3, c8 = f8 & 7;
      size_t goff = (size_t)(t * 64 + row) * CHD + c8 * 8;
      union { uint4 u; unsigned short s[8]; } ck, cw;
      ck.u = *(const uint4*)(kbase + goff);
      cw.u = *(const uint4*)(vbase + goff);
      #pragma unroll
      for (int e = 0; e < 8; ++e) {
        Ks[row][c8 * 8 + e] = bf2f(ck.s[e]);
        Vs[row][c8 * 8 + e] = bf2f(cw.s[e]);
      }
    }
    __syncthreads();
    // scores for this thread's q row
    float cm = -1e30f;
    #pragma unroll 2
    for (int j = 0; j < 64; ++j) {
      const float4* kr = (const float4*)Ks[j];
      float a0 = 0.f, a1 = 0.f, a2 = 0.f, a3 = 0.f;
      #pragma unroll
      for (int dd = 0; dd < 16; ++dd) {
        float4 kv = kr[dd];
        a0 = fmaf(q[dd * 4 + 0], kv.x, a0);
        a1 = fmaf(q[dd * 4 + 1], kv.y, a1);
        a2 = fmaf(q[dd * 4 + 2], kv.z, a2);
        a3 = fmaf(q[dd * 4 + 3], kv.w, a3);
      }
      float sv = ((a0 + a1) + (a2 + a3)) * 0.125f;   // 1/sqrt(64)
      sv = ((t * 64 + j) <= qi) ? sv : -1e30f;       // causal
      Ss[tid][j] = sv;
      cm = fmaxf(cm, sv);
    }
    float nm = fmaxf(m, cm);
    float scale = __expf(m - nm);
    l *= scale;
    #pragma unroll
    for (int d = 0; d < 64; ++d) o[d] *= scale;
    #pragma unroll 2
    for (int j = 0; j < 64; ++j) {
      float p = __expf(Ss[tid][j] - nm);
      l += p;
      const float4* vr = (const float4*)Vs[j];
      #pragma unroll
      for (int dd = 0; dd < 16; ++dd) {
        float4 vv = vr[dd];
        o[dd * 4 + 0] = fmaf(p, vv.x, o[dd * 4 + 0]);
        o[dd * 4 + 1] = fmaf(p, vv.y, o[dd * 4 + 1]);
        o[dd * 4 + 2] = fmaf(p, vv.z, o[dd * 4 + 2]);
        o[dd * 4 + 3] = fmaf(p, vv.w, o[dd * 4 + 3]);
      }
    }
    m = nm;
  }
  float inv = 1.0f / l;
  float* orow = of + (size_t)(b * CS + qi) * CNQ + h * CHD;
  #pragma unroll
  for (int dd = 0; dd < 16; ++dd) {
    float4 ov = make_float4(o[dd * 4] * inv, o[dd * 4 + 1] * inv,
                            o[dd * 4 + 2] * inv, o[dd * 4 + 3] * inv);
    *(float4*)&orow[dd * 4] = ov;
  }
}

// ---------------------------------------------------------------------------
extern "C" void kernel_launch(void* const* d_in, const int* in_sizes, int n_in,
                              void* d_out, int out_size, void* d_ws, size_t ws_size,
                              hipStream_t stream)
{
  const float* x  = (const float*)d_in[0];
  const float* wq = (const float*)d_in[1];
  const float* wk = (const float*)d_in[2];
  const float* wv = (const float*)d_in[3];
  const float* wo = (const float*)d_in[4];
  const float* fc = (const float*)d_in[5];
  const float* fs = (const float*)d_in[6];
  // d_in[7] = mask: exact causal tril, implemented directly in flash_kernel.
  float* out = (float*)d_out;

  char* ws = (char*)d_ws;
  // layout (bytes):
  //   q_f32 : 0        .. 16777216   (reused as o_f32 after rope_q)
  //   k_f32 : 16777216 .. 20971520
  //   v_f32 : 20971520 .. 25165824
  //   q_bf  : 25165824 .. 33554432
  //   k_bf  : 33554432 .. 35651584
  //   v_bf  : 35651584 .. 37748736
  float* q_f = (float*)(ws);
  float* k_f = (float*)(ws + 16777216);
  float* v_f = (float*)(ws + 20971520);
  bf16*  q_b = (bf16*)(ws + 25165824);
  bf16*  k_b = (bf16*)(ws + 33554432);
  bf16*  v_b = (bf16*)(ws + 35651584);
  float* o_f = q_f;  // q_f32 dead after rope_q

  gemm_f32_kernel<<<dim3(CM / 64, CNQ / 64), 256, 0, stream>>>(x, wq, q_f, CM, CNQ, CD);
  gemm_f32_kernel<<<dim3(CM / 64, CNKV / 64), 256, 0, stream>>>(x, wk, k_f, CM, CNKV, CD);
  gemm_f32_kernel<<<dim3(CM / 64, CNKV / 64), 256, 0, stream>>>(x, wv, v_f, CM, CNKV, CD);
  rope_q_kernel<<<(CB * CS * CH * 32) / 256, 256, 0, stream>>>(q_f, fc, fs, q_b);
  rope_k_kernel<<<(CB * CS * CKH * 32) / 256, 256, 0, stream>>>(k_f, fc, fs, k_b);
  conv_v_kernel<<<(CB * CS * CKH * 64) / 256, 256, 0, stream>>>(v_f, v_b);
  flash_kernel<<<CB * CH * (CS / 64), 64, 0, stream>>>(q_b, k_b, v_b, o_f);
  gemm_f32_kernel<<<dim3(CM / 64, CD / 64), 256, 0, stream>>>(o_f, wo, out, CM, CD, CNQ);
}

// Round 2
// 533.573 us; speedup vs baseline: 8.0062x; 8.0062x over previous
//
#include <hip/hip_runtime.h>
#include <hip/hip_bf16.h>

using bf16 = __hip_bfloat16;
typedef short bf16x8 __attribute__((ext_vector_type(8)));
typedef float f32x4 __attribute__((ext_vector_type(4)));

#define CB 2
#define CS 2048
#define CD 1024
#define CH 16
#define CKH 4
#define CHD 64
#define CREP 4
#define CNQ (CH*CHD)    // 1024
#define CNKV (CKH*CHD)  // 256
#define CM (CB*CS)      // 4096

__device__ __forceinline__ float bf2f(unsigned short u) {
  union { unsigned int i; float f; } c;
  c.i = ((unsigned int)u) << 16;
  return c.f;
}
__device__ __forceinline__ unsigned short f2bf(float f) {
  union { float f; unsigned int i; } c; c.f = f;
  unsigned int r = c.i + 0x7FFFu + ((c.i >> 16) & 1u);  // RNE
  return (unsigned short)(r >> 16);
}

// ---------------------------------------------------------------------------
// Generic fp32 tiled GEMM: C[M,N] = A[M,K] @ W[K,N] (unchanged from R1).
// ---------------------------------------------------------------------------
__global__ __launch_bounds__(256) void gemm_f32_kernel(
    const float* __restrict__ A, const float* __restrict__ W,
    float* __restrict__ C, int Mm, int Nn, int Kk)
{
  __shared__ __align__(16) float As[16][68];
  __shared__ __align__(16) float Ws[16][68];
  const int tid = threadIdx.x;
  const int tx = tid & 15, ty = tid >> 4;
  const int mBase = blockIdx.x * 64;
  const int nBase = blockIdx.y * 64;
  float acc[4][4] = {{0.f}};
  for (int k0 = 0; k0 < Kk; k0 += 16) {
    #pragma unroll
    for (int it = 0; it < 4; ++it) {
      int e = tid + it * 256;
      int r = e >> 4, kk = e & 15;
      As[kk][r] = A[(size_t)(mBase + r) * Kk + (k0 + kk)];
      int kw = e >> 6, n = e & 63;
      Ws[kw][n] = W[(size_t)(k0 + kw) * Nn + (nBase + n)];
    }
    __syncthreads();
    #pragma unroll
    for (int kk = 0; kk < 16; ++kk) {
      float4 av = *(const float4*)&As[kk][ty * 4];
      float4 bv = *(const float4*)&Ws[kk][tx * 4];
      float a_[4] = {av.x, av.y, av.z, av.w};
      float b_[4] = {bv.x, bv.y, bv.z, bv.w};
      #pragma unroll
      for (int i = 0; i < 4; ++i)
        #pragma unroll
        for (int j = 0; j < 4; ++j)
          acc[i][j] = fmaf(a_[i], b_[j], acc[i][j]);
    }
    __syncthreads();
  }
  #pragma unroll
  for (int i = 0; i < 4; ++i) {
    float4 o = make_float4(acc[i][0], acc[i][1], acc[i][2], acc[i][3]);
    *(float4*)&C[(size_t)(mBase + ty * 4 + i) * Nn + nBase + tx * 4] = o;
  }
}

// ---------------------------------------------------------------------------
// RoPE q: f32 [B,S,H*HD] -> bf16 [B,H,S,HD]
// ---------------------------------------------------------------------------
__global__ void rope_q_kernel(const float* __restrict__ qf,
                              const float* __restrict__ fc,
                              const float* __restrict__ fs,
                              bf16* __restrict__ qb)
{
  int p = blockIdx.x * blockDim.x + threadIdx.x;
  int j = p & 31;
  int h = (p >> 5) & 15;
  int s = (p >> 9) & 2047;
  int b = p >> 20;
  const float* src = qf + (size_t)(b * CS + s) * CNQ + h * CHD + j * 2;
  float x0 = src[0], x1 = src[1];
  float c = fc[s * 32 + j], sn = fs[s * 32 + j];
  bf16* dst = qb + ((size_t)(b * CH + h) * CS + s) * CHD + j * 2;
  dst[0] = __float2bfloat16(x0 * c - x1 * sn);
  dst[1] = __float2bfloat16(x0 * sn + x1 * c);
}

__global__ void rope_k_kernel(const float* __restrict__ kf,
                              const float* __restrict__ fc,
                              const float* __restrict__ fs,
                              bf16* __restrict__ kb)
{
  int p = blockIdx.x * blockDim.x + threadIdx.x;
  int j = p & 31;
  int kh = (p >> 5) & 3;
  int s = (p >> 7) & 2047;
  int b = p >> 18;
  const float* src = kf + (size_t)(b * CS + s) * CNKV + kh * CHD + j * 2;
  float x0 = src[0], x1 = src[1];
  float c = fc[s * 32 + j], sn = fs[s * 32 + j];
  bf16* dst = kb + ((size_t)(b * CKH + kh) * CS + s) * CHD + j * 2;
  dst[0] = __float2bfloat16(x0 * c - x1 * sn);
  dst[1] = __float2bfloat16(x0 * sn + x1 * c);
}

__global__ void conv_v_kernel(const float* __restrict__ vf, bf16* __restrict__ vb)
{
  int e = blockIdx.x * blockDim.x + threadIdx.x;
  int d = e & 63;
  int kh = (e >> 6) & 3;
  int s = (e >> 8) & 2047;
  int b = e >> 19;
  vb[((size_t)(b * CKH + kh) * CS + s) * CHD + d] =
      __float2bfloat16(vf[(size_t)(b * CS + s) * CNKV + kh * CHD + d]);
}

// ---------------------------------------------------------------------------
// MFMA flash attention.
// Block = 4 waves = 4 q-heads of one kv-head group; each wave owns 32 q rows.
// Grid = B * KH * (S/32) = 512 blocks of 256 threads.
// Swapped QK^T: S^T = mfma(K_frag, Q_frag)  (C/D: col=lane&15=q, row k=(g)*4+reg)
// Swapped PV:   O^T = mfma(VT_frag, P_frag) (col=q, row d — regs = 4 consec. d)
// K/Q fragments read directly from global (L2-resident); V^T staged in LDS
// (shared across waves); P routed per-wave through LDS as [q][k] bf16.
// A/B-frag k-placement is identical for both operands of each mfma, so the
// (unverified) hardware k-mapping cancels; mask/P-store use only the verified
// C/D layout.
// ---------------------------------------------------------------------------
__global__ __launch_bounds__(256) void flash_mfma_kernel(
    const bf16* __restrict__ qb, const bf16* __restrict__ kb,
    const bf16* __restrict__ vb, float* __restrict__ of)
{
  __shared__ __align__(16) unsigned short VT[64][40];      // V^T [d][k], pad 40
  __shared__ __align__(16) unsigned short PL[4][32][40];   // per-wave P [q][k]
  const int tid = threadIdx.x;
  const int lane = tid & 63;
  const int wid = tid >> 6;
  const int l15 = lane & 15;
  const int g = lane >> 4;
  const int blk = blockIdx.x;
  const int qt = blk & 63;            // S/32 = 64 q-tiles
  const int kh = (blk >> 6) & 3;
  const int b = blk >> 8;
  const int h = kh * CREP + wid;

  const bf16* qbase = qb + ((size_t)(b * CH + h) * CS + qt * 32) * CHD;
  const bf16* kbase = kb + (size_t)(b * CKH + kh) * CS * CHD;
  const bf16* vbase = vb + (size_t)(b * CKH + kh) * CS * CHD;

  // Q B-fragments, held in registers: [q-set][hd-chunk]
  bf16x8 qf[2][2];
  #pragma unroll
  for (int qs = 0; qs < 2; ++qs)
    #pragma unroll
    for (int c = 0; c < 2; ++c)
      qf[qs][c] = *(const bf16x8*)(qbase + (qs * 16 + l15) * CHD + c * 32 + g * 8);

  f32x4 oacc[2][4];                  // O^T acc: [q-set][d-tile]
  #pragma unroll
  for (int qs = 0; qs < 2; ++qs)
    #pragma unroll
    for (int dt = 0; dt < 4; ++dt)
      oacc[qs][dt] = (f32x4){0.f, 0.f, 0.f, 0.f};
  float mrow[2] = {-1e30f, -1e30f};
  float lrow[2] = {0.f, 0.f};

  for (int t = 0; t <= qt; ++t) {
    __syncthreads();
    // stage V^T tile: V[t*32 .. +31][0..63] -> VT[d][k]
    {
      int kr = tid >> 3;             // 0..31
      int d0 = (tid & 7) * 8;
      bf16x8 vv = *(const bf16x8*)(vbase + (size_t)(t * 32 + kr) * CHD + d0);
      #pragma unroll
      for (int e = 0; e < 8; ++e)
        VT[d0 + e][kr] = (unsigned short)vv[e];
    }
    __syncthreads();

    // QK^T -> S^T acc [k-tile][q-set]
    f32x4 sacc[2][2];
    #pragma unroll
    for (int kt = 0; kt < 2; ++kt)
      #pragma unroll
      for (int qs = 0; qs < 2; ++qs)
        sacc[kt][qs] = (f32x4){0.f, 0.f, 0.f, 0.f};
    #pragma unroll
    for (int c = 0; c < 2; ++c) {
      #pragma unroll
      for (int kt = 0; kt < 2; ++kt) {
        bf16x8 kf = *(const bf16x8*)(kbase + (size_t)(t * 32 + kt * 16 + l15) * CHD + c * 32 + g * 8);
        #pragma unroll
        for (int qs = 0; qs < 2; ++qs)
          sacc[kt][qs] = __builtin_amdgcn_mfma_f32_16x16x32_bf16(kf, qf[qs][c], sacc[kt][qs], 0, 0, 0);
      }
    }

    // online softmax per q-set
    #pragma unroll
    for (int qs = 0; qs < 2; ++qs) {
      float s[8];
      float pm = -1e30f;
      #pragma unroll
      for (int kt = 0; kt < 2; ++kt)
        #pragma unroll
        for (int r = 0; r < 4; ++r) {
          float v = sacc[kt][qs][r] * 0.125f;    // 1/sqrt(64)
          if (t == qt) {
            int koff = kt * 16 + 4 * g + r;
            int qoff = qs * 16 + l15;
            if (koff > qoff) v = -1e30f;         // causal
          }
          s[kt * 4 + r] = v;
          pm = fmaxf(pm, v);
        }
      pm = fmaxf(pm, __shfl_xor(pm, 16, 64));
      pm = fmaxf(pm, __shfl_xor(pm, 32, 64));
      float nm = fmaxf(mrow[qs], pm);
      float corr = __expf(mrow[qs] - nm);
      mrow[qs] = nm;
      float psum = 0.f;
      unsigned short pb[8];
      #pragma unroll
      for (int i = 0; i < 8; ++i) {
        float p = __expf(s[i] - nm);
        psum += p;
        pb[i] = f2bf(p);
      }
      psum += __shfl_xor(psum, 16, 64);
      psum += __shfl_xor(psum, 32, 64);
      lrow[qs] = lrow[qs] * corr + psum;
      #pragma unroll
      for (int dt = 0; dt < 4; ++dt)
        oacc[qs][dt] *= corr;
      // write P^T rows: regs are 4 consecutive k -> one 8B store per k-tile
      #pragma unroll
      for (int kt = 0; kt < 2; ++kt)
        *(ushort4*)&PL[wid][qs * 16 + l15][kt * 16 + 4 * g] =
            make_ushort4(pb[kt * 4 + 0], pb[kt * 4 + 1], pb[kt * 4 + 2], pb[kt * 4 + 3]);
    }
    __syncthreads();   // P/VT visible (also keeps waves in lockstep for VT reuse)

    // PV: O^T += V^T · P^T
    #pragma unroll
    for (int qs = 0; qs < 2; ++qs) {
      bf16x8 pf = *(const bf16x8*)&PL[wid][qs * 16 + l15][g * 8];
      #pragma unroll
      for (int dt = 0; dt < 4; ++dt) {
        bf16x8 vf = *(const bf16x8*)&VT[dt * 16 + l15][g * 8];
        oacc[qs][dt] = __builtin_amdgcn_mfma_f32_16x16x32_bf16(vf, pf, oacc[qs][dt], 0, 0, 0);
      }
    }
  }

  // epilogue: normalize, write O rows (regs = 4 consecutive d -> float4 store)
  #pragma unroll
  for (int qs = 0; qs < 2; ++qs) {
    float inv = 1.0f / lrow[qs];
    int qg = qt * 32 + qs * 16 + l15;
    float* orow = of + (size_t)(b * CS + qg) * CNQ + h * CHD;
    #pragma unroll
    for (int dt = 0; dt < 4; ++dt) {
      float4 o = make_float4(oacc[qs][dt][0] * inv, oacc[qs][dt][1] * inv,
                             oacc[qs][dt][2] * inv, oacc[qs][dt][3] * inv);
      *(float4*)&orow[dt * 16 + 4 * g] = o;
    }
  }
}

// ---------------------------------------------------------------------------
extern "C" void kernel_launch(void* const* d_in, const int* in_sizes, int n_in,
                              void* d_out, int out_size, void* d_ws, size_t ws_size,
                              hipStream_t stream)
{
  const float* x  = (const float*)d_in[0];
  const float* wq = (const float*)d_in[1];
  const float* wk = (const float*)d_in[2];
  const float* wv = (const float*)d_in[3];
  const float* wo = (const float*)d_in[4];
  const float* fc = (const float*)d_in[5];
  const float* fs = (const float*)d_in[6];
  float* out = (float*)d_out;

  char* ws = (char*)d_ws;
  float* q_f = (float*)(ws);
  float* k_f = (float*)(ws + 16777216);
  float* v_f = (float*)(ws + 20971520);
  bf16*  q_b = (bf16*)(ws + 25165824);
  bf16*  k_b = (bf16*)(ws + 33554432);
  bf16*  v_b = (bf16*)(ws + 35651584);
  float* o_f = q_f;  // q_f32 dead after rope_q

  gemm_f32_kernel<<<dim3(CM / 64, CNQ / 64), 256, 0, stream>>>(x, wq, q_f, CM, CNQ, CD);
  gemm_f32_kernel<<<dim3(CM / 64, CNKV / 64), 256, 0, stream>>>(x, wk, k_f, CM, CNKV, CD);
  gemm_f32_kernel<<<dim3(CM / 64, CNKV / 64), 256, 0, stream>>>(x, wv, v_f, CM, CNKV, CD);
  rope_q_kernel<<<(CB * CS * CH * 32) / 256, 256, 0, stream>>>(q_f, fc, fs, q_b);
  rope_k_kernel<<<(CB * CS * CKH * 32) / 256, 256, 0, stream>>>(k_f, fc, fs, k_b);
  conv_v_kernel<<<(CB * CS * CKH * 64) / 256, 256, 0, stream>>>(v_f, v_b);
  flash_mfma_kernel<<<CB * CKH * (CS / 32), 256, 0, stream>>>(q_b, k_b, v_b, o_f);
  gemm_f32_kernel<<<dim3(CM / 64, CD / 64), 256, 0, stream>>>(o_f, wo, out, CM, CD, CNQ);
}

// Round 3
// 283.146 us; speedup vs baseline: 15.0873x; 1.8844x over previous
//
#include <hip/hip_runtime.h>
#include <hip/hip_bf16.h>

using bf16 = __hip_bfloat16;
typedef short bf16x8 __attribute__((ext_vector_type(8)));
typedef float f32x4 __attribute__((ext_vector_type(4)));

#define CB 2
#define CS 2048
#define CD 1024
#define CH 16
#define CKH 4
#define CHD 64
#define CREP 4
#define CNQ (CH*CHD)    // 1024
#define CNKV (CKH*CHD)  // 256
#define CM (CB*CS)      // 4096

__device__ __forceinline__ float bf2f(unsigned short u) {
  union { unsigned int i; float f; } c;
  c.i = ((unsigned int)u) << 16;
  return c.f;
}
__device__ __forceinline__ unsigned short f2bf(float f) {
  union { float f; unsigned int i; } c; c.f = f;
  unsigned int r = c.i + 0x7FFFu + ((c.i >> 16) & 1u);  // RNE
  return (unsigned short)(r >> 16);
}
__device__ __forceinline__ void gload_lds16(const void* g, void* l) {
  __builtin_amdgcn_global_load_lds(
      (const __attribute__((address_space(1))) void*)g,
      (__attribute__((address_space(3))) void*)l, 16, 0, 0);
}

// ---------------------------------------------------------------------------
// bf16 MFMA GEMM: C[M,N] f32 = A[M,K] bf16 · Bt[N,K]^T bf16.
// 128x128 tile, BK=32, 256 threads = 4 waves (2x2 of 64x64), m97 structure:
// global_load_lds(16B) staging (linear LDS), ds_read_b128 fragments,
// 16 mfma_16x16x32 per wave per K-step. BK=32 -> 64B LDS rows -> fragment
// reads naturally spread over all 8 chunk-columns (no swizzle needed).
// ---------------------------------------------------------------------------
__global__ __launch_bounds__(256) void gemm_mfma_kernel(
    const bf16* __restrict__ A, const bf16* __restrict__ Bt,
    float* __restrict__ C, int Mm, int Nn, int Kk)
{
  __shared__ __align__(16) bf16 As[128 * 32];
  __shared__ __align__(16) bf16 Bs[128 * 32];
  const int tid = threadIdx.x;
  const int lane = tid & 63;
  const int l15 = lane & 15;
  const int g = lane >> 4;
  const int wid = tid >> 6;
  const int wr = (wid >> 1) * 64;
  const int wc = (wid & 1) * 64;
  const int m0 = blockIdx.x * 128;
  const int n0 = blockIdx.y * 128;

  f32x4 acc[4][4];
  #pragma unroll
  for (int i = 0; i < 4; ++i)
    #pragma unroll
    for (int j = 0; j < 4; ++j)
      acc[i][j] = (f32x4){0.f, 0.f, 0.f, 0.f};

  const int sr = tid >> 2;          // staging row 0..63 (iter 0)
  const int sc = (tid & 3) * 8;     // staging k-chunk
  const bf16* aSrc0 = A + (size_t)(m0 + sr) * Kk + sc;
  const bf16* aSrc1 = A + (size_t)(m0 + 64 + sr) * Kk + sc;
  const bf16* bSrc0 = Bt + (size_t)(n0 + sr) * Kk + sc;
  const bf16* bSrc1 = Bt + (size_t)(n0 + 64 + sr) * Kk + sc;
  bf16* aDstW = &As[(tid & 192) * 8];   // wave-uniform linear LDS base
  bf16* bDstW = &Bs[(tid & 192) * 8];

  for (int k0 = 0; k0 < Kk; k0 += 32) {
    gload_lds16(aSrc0 + k0, aDstW);
    gload_lds16(aSrc1 + k0, aDstW + 2048);
    gload_lds16(bSrc0 + k0, bDstW);
    gload_lds16(bSrc1 + k0, bDstW + 2048);
    __syncthreads();                 // drains vmcnt -> LDS tiles ready
    bf16x8 af[4], bfr[4];
    #pragma unroll
    for (int mt = 0; mt < 4; ++mt)
      af[mt] = *(const bf16x8*)&As[(wr + mt * 16 + l15) * 32 + g * 8];
    #pragma unroll
    for (int nt = 0; nt < 4; ++nt)
      bfr[nt] = *(const bf16x8*)&Bs[(wc + nt * 16 + l15) * 32 + g * 8];
    #pragma unroll
    for (int mt = 0; mt < 4; ++mt)
      #pragma unroll
      for (int nt = 0; nt < 4; ++nt)
        acc[mt][nt] = __builtin_amdgcn_mfma_f32_16x16x32_bf16(af[mt], bfr[nt], acc[mt][nt], 0, 0, 0);
    __syncthreads();                 // protect LDS before next-tile staging
  }

  // epilogue: C/D layout col=lane&15 (n), row=4*g+reg (m)
  #pragma unroll
  for (int mt = 0; mt < 4; ++mt)
    #pragma unroll
    for (int r4 = 0; r4 < 4; ++r4) {
      const size_t row = (size_t)(m0 + wr + mt * 16 + 4 * g + r4);
      #pragma unroll
      for (int nt = 0; nt < 4; ++nt)
        C[row * Nn + n0 + wc + nt * 16 + l15] = acc[mt][nt][r4];
    }
}

// ---------------------------------------------------------------------------
// x f32 -> bf16, elementwise, 8 elems/thread.
// ---------------------------------------------------------------------------
__global__ void conv_x_kernel(const float* __restrict__ x, bf16* __restrict__ xb)
{
  int i = (blockIdx.x * 256 + threadIdx.x) * 8;
  float4 a = *(const float4*)&x[i];
  float4 b = *(const float4*)&x[i + 4];
  unsigned short* o = (unsigned short*)xb + i;
  *(ushort4*)o = make_ushort4(f2bf(a.x), f2bf(a.y), f2bf(a.z), f2bf(a.w));
  *(ushort4*)(o + 4) = make_ushort4(f2bf(b.x), f2bf(b.y), f2bf(b.z), f2bf(b.w));
}

// ---------------------------------------------------------------------------
// W[K][N] f32 -> Wt[N][K] bf16 (LDS-tiled 64x64 transpose + convert).
// ---------------------------------------------------------------------------
__global__ __launch_bounds__(256) void transpose_conv_kernel(
    const float* __restrict__ W, bf16* __restrict__ Wt, int Kk, int Nn)
{
  __shared__ float T[64][65];
  const int k0 = blockIdx.x * 64;
  const int n0 = blockIdx.y * 64;
  const int tid = threadIdx.x;
  const int lr = tid >> 4;
  const int lc = (tid & 15) * 4;
  #pragma unroll
  for (int i = 0; i < 4; ++i) {
    float4 v = *(const float4*)&W[(size_t)(k0 + lr + i * 16) * Nn + n0 + lc];
    T[lr + i * 16][lc + 0] = v.x;
    T[lr + i * 16][lc + 1] = v.y;
    T[lr + i * 16][lc + 2] = v.z;
    T[lr + i * 16][lc + 3] = v.w;
  }
  __syncthreads();
  const int rn = tid >> 3;
  const int ck = (tid & 7) * 8;
  #pragma unroll
  for (int i = 0; i < 2; ++i) {
    int nn = rn + i * 32;
    unsigned short u[8];
    #pragma unroll
    for (int e = 0; e < 8; ++e) u[e] = f2bf(T[ck + e][nn]);
    unsigned short* dst = (unsigned short*)Wt + (size_t)(n0 + nn) * Kk + k0 + ck;
    *(ushort4*)dst = make_ushort4(u[0], u[1], u[2], u[3]);
    *(ushort4*)(dst + 4) = make_ushort4(u[4], u[5], u[6], u[7]);
  }
}

// ---------------------------------------------------------------------------
// RoPE q: f32 [B,S,H*HD] -> bf16 [B,H,S,HD]
// ---------------------------------------------------------------------------
__global__ void rope_q_kernel(const float* __restrict__ qf,
                              const float* __restrict__ fc,
                              const float* __restrict__ fs,
                              bf16* __restrict__ qb)
{
  int p = blockIdx.x * blockDim.x + threadIdx.x;
  int j = p & 31;
  int h = (p >> 5) & 15;
  int s = (p >> 9) & 2047;
  int b = p >> 20;
  const float* src = qf + (size_t)(b * CS + s) * CNQ + h * CHD + j * 2;
  float x0 = src[0], x1 = src[1];
  float c = fc[s * 32 + j], sn = fs[s * 32 + j];
  bf16* dst = qb + ((size_t)(b * CH + h) * CS + s) * CHD + j * 2;
  dst[0] = __float2bfloat16(x0 * c - x1 * sn);
  dst[1] = __float2bfloat16(x0 * sn + x1 * c);
}

__global__ void rope_k_kernel(const float* __restrict__ kf,
                              const float* __restrict__ fc,
                              const float* __restrict__ fs,
                              bf16* __restrict__ kb)
{
  int p = blockIdx.x * blockDim.x + threadIdx.x;
  int j = p & 31;
  int kh = (p >> 5) & 3;
  int s = (p >> 7) & 2047;
  int b = p >> 18;
  const float* src = kf + (size_t)(b * CS + s) * CNKV + kh * CHD + j * 2;
  float x0 = src[0], x1 = src[1];
  float c = fc[s * 32 + j], sn = fs[s * 32 + j];
  bf16* dst = kb + ((size_t)(b * CKH + kh) * CS + s) * CHD + j * 2;
  dst[0] = __float2bfloat16(x0 * c - x1 * sn);
  dst[1] = __float2bfloat16(x0 * sn + x1 * c);
}

__global__ void conv_v_kernel(const float* __restrict__ vf, bf16* __restrict__ vb)
{
  int e = blockIdx.x * blockDim.x + threadIdx.x;
  int d = e & 63;
  int kh = (e >> 6) & 3;
  int s = (e >> 8) & 2047;
  int b = e >> 19;
  vb[((size_t)(b * CKH + kh) * CS + s) * CHD + d] =
      __float2bfloat16(vf[(size_t)(b * CS + s) * CNKV + kh * CHD + d]);
}

// ---------------------------------------------------------------------------
// MFMA flash attention (R2 structure), now emitting bf16 O directly.
// ---------------------------------------------------------------------------
__global__ __launch_bounds__(256) void flash_mfma_kernel(
    const bf16* __restrict__ qb, const bf16* __restrict__ kb,
    const bf16* __restrict__ vb, bf16* __restrict__ ob)
{
  __shared__ __align__(16) unsigned short VT[64][40];      // V^T [d][k]
  __shared__ __align__(16) unsigned short PL[4][32][40];   // per-wave P [q][k]
  const int tid = threadIdx.x;
  const int lane = tid & 63;
  const int wid = tid >> 6;
  const int l15 = lane & 15;
  const int g = lane >> 4;
  const int blk = blockIdx.x;
  const int qt = blk & 63;
  const int kh = (blk >> 6) & 3;
  const int b = blk >> 8;
  const int h = kh * CREP + wid;

  const bf16* qbase = qb + ((size_t)(b * CH + h) * CS + qt * 32) * CHD;
  const bf16* kbase = kb + (size_t)(b * CKH + kh) * CS * CHD;
  const bf16* vbase = vb + (size_t)(b * CKH + kh) * CS * CHD;

  bf16x8 qf[2][2];
  #pragma unroll
  for (int qs = 0; qs < 2; ++qs)
    #pragma unroll
    for (int c = 0; c < 2; ++c)
      qf[qs][c] = *(const bf16x8*)(qbase + (qs * 16 + l15) * CHD + c * 32 + g * 8);

  f32x4 oacc[2][4];
  #pragma unroll
  for (int qs = 0; qs < 2; ++qs)
    #pragma unroll
    for (int dt = 0; dt < 4; ++dt)
      oacc[qs][dt] = (f32x4){0.f, 0.f, 0.f, 0.f};
  float mrow[2] = {-1e30f, -1e30f};
  float lrow[2] = {0.f, 0.f};

  for (int t = 0; t <= qt; ++t) {
    __syncthreads();
    {
      int kr = tid >> 3;
      int d0 = (tid & 7) * 8;
      bf16x8 vv = *(const bf16x8*)(vbase + (size_t)(t * 32 + kr) * CHD + d0);
      #pragma unroll
      for (int e = 0; e < 8; ++e)
        VT[d0 + e][kr] = (unsigned short)vv[e];
    }
    __syncthreads();

    f32x4 sacc[2][2];
    #pragma unroll
    for (int kt = 0; kt < 2; ++kt)
      #pragma unroll
      for (int qs = 0; qs < 2; ++qs)
        sacc[kt][qs] = (f32x4){0.f, 0.f, 0.f, 0.f};
    #pragma unroll
    for (int c = 0; c < 2; ++c) {
      #pragma unroll
      for (int kt = 0; kt < 2; ++kt) {
        bf16x8 kf = *(const bf16x8*)(kbase + (size_t)(t * 32 + kt * 16 + l15) * CHD + c * 32 + g * 8);
        #pragma unroll
        for (int qs = 0; qs < 2; ++qs)
          sacc[kt][qs] = __builtin_amdgcn_mfma_f32_16x16x32_bf16(kf, qf[qs][c], sacc[kt][qs], 0, 0, 0);
      }
    }

    #pragma unroll
    for (int qs = 0; qs < 2; ++qs) {
      float s[8];
      float pm = -1e30f;
      #pragma unroll
      for (int kt = 0; kt < 2; ++kt)
        #pragma unroll
        for (int r = 0; r < 4; ++r) {
          float v = sacc[kt][qs][r] * 0.125f;
          if (t == qt) {
            int koff = kt * 16 + 4 * g + r;
            int qoff = qs * 16 + l15;
            if (koff > qoff) v = -1e30f;
          }
          s[kt * 4 + r] = v;
          pm = fmaxf(pm, v);
        }
      pm = fmaxf(pm, __shfl_xor(pm, 16, 64));
      pm = fmaxf(pm, __shfl_xor(pm, 32, 64));
      float nm = fmaxf(mrow[qs], pm);
      float corr = __expf(mrow[qs] - nm);
      mrow[qs] = nm;
      float psum = 0.f;
      unsigned short pb[8];
      #pragma unroll
      for (int i = 0; i < 8; ++i) {
        float p = __expf(s[i] - nm);
        psum += p;
        pb[i] = f2bf(p);
      }
      psum += __shfl_xor(psum, 16, 64);
      psum += __shfl_xor(psum, 32, 64);
      lrow[qs] = lrow[qs] * corr + psum;
      #pragma unroll
      for (int dt = 0; dt < 4; ++dt)
        oacc[qs][dt] *= corr;
      #pragma unroll
      for (int kt = 0; kt < 2; ++kt)
        *(ushort4*)&PL[wid][qs * 16 + l15][kt * 16 + 4 * g] =
            make_ushort4(pb[kt * 4 + 0], pb[kt * 4 + 1], pb[kt * 4 + 2], pb[kt * 4 + 3]);
    }
    __syncthreads();

    #pragma unroll
    for (int qs = 0; qs < 2; ++qs) {
      bf16x8 pf = *(const bf16x8*)&PL[wid][qs * 16 + l15][g * 8];
      #pragma unroll
      for (int dt = 0; dt < 4; ++dt) {
        bf16x8 vf = *(const bf16x8*)&VT[dt * 16 + l15][g * 8];
        oacc[qs][dt] = __builtin_amdgcn_mfma_f32_16x16x32_bf16(vf, pf, oacc[qs][dt], 0, 0, 0);
      }
    }
  }

  #pragma unroll
  for (int qs = 0; qs < 2; ++qs) {
    float inv = 1.0f / lrow[qs];
    int qg = qt * 32 + qs * 16 + l15;
    unsigned short* orow = (unsigned short*)ob + (size_t)(b * CS + qg) * CNQ + h * CHD;
    #pragma unroll
    for (int dt = 0; dt < 4; ++dt) {
      *(ushort4*)&orow[dt * 16 + 4 * g] =
          make_ushort4(f2bf(oacc[qs][dt][0] * inv), f2bf(oacc[qs][dt][1] * inv),
                       f2bf(oacc[qs][dt][2] * inv), f2bf(oacc[qs][dt][3] * inv));
    }
  }
}

// ---------------------------------------------------------------------------
extern "C" void kernel_launch(void* const* d_in, const int* in_sizes, int n_in,
                              void* d_out, int out_size, void* d_ws, size_t ws_size,
                              hipStream_t stream)
{
  const float* x  = (const float*)d_in[0];
  const float* wq = (const float*)d_in[1];
  const float* wk = (const float*)d_in[2];
  const float* wv = (const float*)d_in[3];
  const float* wo = (const float*)d_in[4];
  const float* fc = (const float*)d_in[5];
  const float* fs = (const float*)d_in[6];
  float* out = (float*)d_out;

  char* ws = (char*)d_ws;
  // live-range-packed workspace (max 36.7 MB):
  bf16*  x_b = (bf16*)(ws);                      // [0, 8M)   dead after v-GEMM
  float* q_f = (float*)(ws + 8388608);           // [8M, 25M) dead after rope_q
  float* k_f = (float*)(ws + 25165824);          // [25M,29M) dead after rope_k
  float* v_f = (float*)(ws + 29360128);          // [29M,33.5M) dead after conv_v
  bf16*  wqt = (bf16*)(ws + 33554432);
  bf16*  wkt = (bf16*)(ws + 35651584);
  bf16*  wvt = (bf16*)(ws + 36175872);
  bf16*  q_b = (bf16*)(ws);                      // reuse x_b region
  bf16*  k_b = (bf16*)(ws + 8388608);            // reuse q_f region
  bf16*  v_b = (bf16*)(ws + 10485760);
  bf16*  o_b = (bf16*)(ws + 12582912);
  bf16*  wot = (bf16*)(ws + 25165824);           // reuse k_f region (after rope_k)

  conv_x_kernel<<<2048, 256, 0, stream>>>(x, x_b);
  transpose_conv_kernel<<<dim3(16, 16), 256, 0, stream>>>(wq, wqt, CD, CNQ);
  transpose_conv_kernel<<<dim3(16, 4), 256, 0, stream>>>(wk, wkt, CD, CNKV);
  transpose_conv_kernel<<<dim3(16, 4), 256, 0, stream>>>(wv, wvt, CD, CNKV);
  gemm_mfma_kernel<<<dim3(32, 8), 256, 0, stream>>>(x_b, wqt, q_f, CM, CNQ, CD);
  gemm_mfma_kernel<<<dim3(32, 2), 256, 0, stream>>>(x_b, wkt, k_f, CM, CNKV, CD);
  gemm_mfma_kernel<<<dim3(32, 2), 256, 0, stream>>>(x_b, wvt, v_f, CM, CNKV, CD);
  rope_q_kernel<<<(CB * CS * CH * 32) / 256, 256, 0, stream>>>(q_f, fc, fs, q_b);
  rope_k_kernel<<<(CB * CS * CKH * 32) / 256, 256, 0, stream>>>(k_f, fc, fs, k_b);
  conv_v_kernel<<<(CB * CS * CKH * 64) / 256, 256, 0, stream>>>(v_f, v_b);
  transpose_conv_kernel<<<dim3(16, 16), 256, 0, stream>>>(wo, wot, CNQ, CD);
  flash_mfma_kernel<<<CB * CKH * (CS / 32), 256, 0, stream>>>(q_b, k_b, v_b, o_b);
  gemm_mfma_kernel<<<dim3(32, 8), 256, 0, stream>>>(o_b, wot, out, CM, CD, CNQ);
}

// Round 4
// 211.918 us; speedup vs baseline: 20.1583x; 1.3361x over previous
//
#include <hip/hip_runtime.h>
#include <hip/hip_bf16.h>

using bf16 = __hip_bfloat16;
typedef short bf16x8 __attribute__((ext_vector_type(8)));
typedef float f32x4 __attribute__((ext_vector_type(4)));

#define CB 2
#define CS 2048
#define CD 1024
#define CH 16
#define CKH 4
#define CHD 64
#define CREP 4
#define CNQ (CH*CHD)    // 1024
#define CNKV (CKH*CHD)  // 256
#define CM (CB*CS)      // 4096

__device__ __forceinline__ unsigned short f2bf(float f) {
  union { float f; unsigned int i; } c; c.f = f;
  unsigned int r = c.i + 0x7FFFu + ((c.i >> 16) & 1u);  // RNE
  return (unsigned short)(r >> 16);
}
__device__ __forceinline__ void gload_lds16(const void* g, void* l) {
  __builtin_amdgcn_global_load_lds(
      (const __attribute__((address_space(1))) void*)g,
      (__attribute__((address_space(3))) void*)l, 16, 0, 0);
}

// ---------------------------------------------------------------------------
// bf16 MFMA GEMM: C[M,N] f32 = A[M,K] bf16 · Bt[N,K]^T bf16.
// 64x128 tile, BK=32, 256 threads = 4 waves (2x2, wave tile 32x64).
// global_load_lds(16B) staging, linear LDS (64B rows -> conflict-free reads).
// ---------------------------------------------------------------------------
__global__ __launch_bounds__(256) void gemm_mfma_kernel(
    const bf16* __restrict__ A, const bf16* __restrict__ Bt,
    float* __restrict__ C, int Mm, int Nn, int Kk)
{
  __shared__ __align__(16) bf16 As[64 * 32];
  __shared__ __align__(16) bf16 Bs[128 * 32];
  const int tid = threadIdx.x;
  const int lane = tid & 63;
  const int l15 = lane & 15;
  const int g = lane >> 4;
  const int wid = tid >> 6;
  const int wr = (wid >> 1) * 32;
  const int wc = (wid & 1) * 64;
  const int m0 = blockIdx.x * 64;
  const int n0 = blockIdx.y * 128;

  f32x4 acc[2][4];
  #pragma unroll
  for (int i = 0; i < 2; ++i)
    #pragma unroll
    for (int j = 0; j < 4; ++j)
      acc[i][j] = (f32x4){0.f, 0.f, 0.f, 0.f};

  const int sr = tid >> 2;          // 0..63
  const int sc = (tid & 3) * 8;
  const bf16* aSrc = A + (size_t)(m0 + sr) * Kk + sc;
  const bf16* bSrc0 = Bt + (size_t)(n0 + sr) * Kk + sc;
  const bf16* bSrc1 = Bt + (size_t)(n0 + 64 + sr) * Kk + sc;
  bf16* aDstW = &As[(tid & 192) * 8];          // wave-uniform linear base
  bf16* bDstW = &Bs[(tid & 192) * 8];

  for (int k0 = 0; k0 < Kk; k0 += 32) {
    gload_lds16(aSrc + k0, aDstW);
    gload_lds16(bSrc0 + k0, bDstW);
    gload_lds16(bSrc1 + k0, bDstW + 2048);
    __syncthreads();
    bf16x8 af[2], bfr[4];
    #pragma unroll
    for (int mt = 0; mt < 2; ++mt)
      af[mt] = *(const bf16x8*)&As[(wr + mt * 16 + l15) * 32 + g * 8];
    #pragma unroll
    for (int nt = 0; nt < 4; ++nt)
      bfr[nt] = *(const bf16x8*)&Bs[(wc + nt * 16 + l15) * 32 + g * 8];
    #pragma unroll
    for (int mt = 0; mt < 2; ++mt)
      #pragma unroll
      for (int nt = 0; nt < 4; ++nt)
        acc[mt][nt] = __builtin_amdgcn_mfma_f32_16x16x32_bf16(af[mt], bfr[nt], acc[mt][nt], 0, 0, 0);
    __syncthreads();
  }

  #pragma unroll
  for (int mt = 0; mt < 2; ++mt)
    #pragma unroll
    for (int r4 = 0; r4 < 4; ++r4) {
      const size_t row = (size_t)(m0 + wr + mt * 16 + 4 * g + r4);
      #pragma unroll
      for (int nt = 0; nt < 4; ++nt)
        C[row * Nn + n0 + wc + nt * 16 + l15] = acc[mt][nt][r4];
    }
}

// ---------------------------------------------------------------------------
__global__ void conv_x_kernel(const float* __restrict__ x, bf16* __restrict__ xb)
{
  int i = (blockIdx.x * 256 + threadIdx.x) * 8;
  float4 a = *(const float4*)&x[i];
  float4 b = *(const float4*)&x[i + 4];
  unsigned short* o = (unsigned short*)xb + i;
  *(ushort4*)o = make_ushort4(f2bf(a.x), f2bf(a.y), f2bf(a.z), f2bf(a.w));
  *(ushort4*)(o + 4) = make_ushort4(f2bf(b.x), f2bf(b.y), f2bf(b.z), f2bf(b.w));
}

// W[K][N] f32 -> Wt[N][K] bf16 (LDS-tiled 64x64 transpose + convert).
__global__ __launch_bounds__(256) void transpose_conv_kernel(
    const float* __restrict__ W, bf16* __restrict__ Wt, int Kk, int Nn)
{
  __shared__ float T[64][65];
  const int k0 = blockIdx.x * 64;
  const int n0 = blockIdx.y * 64;
  const int tid = threadIdx.x;
  const int lr = tid >> 4;
  const int lc = (tid & 15) * 4;
  #pragma unroll
  for (int i = 0; i < 4; ++i) {
    float4 v = *(const float4*)&W[(size_t)(k0 + lr + i * 16) * Nn + n0 + lc];
    T[lr + i * 16][lc + 0] = v.x;
    T[lr + i * 16][lc + 1] = v.y;
    T[lr + i * 16][lc + 2] = v.z;
    T[lr + i * 16][lc + 3] = v.w;
  }
  __syncthreads();
  const int rn = tid >> 3;
  const int ck = (tid & 7) * 8;
  #pragma unroll
  for (int i = 0; i < 2; ++i) {
    int nn = rn + i * 32;
    unsigned short u[8];
    #pragma unroll
    for (int e = 0; e < 8; ++e) u[e] = f2bf(T[ck + e][nn]);
    unsigned short* dst = (unsigned short*)Wt + (size_t)(n0 + nn) * Kk + k0 + ck;
    *(ushort4*)dst = make_ushort4(u[0], u[1], u[2], u[3]);
    *(ushort4*)(dst + 4) = make_ushort4(u[4], u[5], u[6], u[7]);
  }
}

// ---------------------------------------------------------------------------
// RoPE q: f32 [B,S,H*HD] -> bf16 [B,H,S,HD]
// ---------------------------------------------------------------------------
__global__ void rope_q_kernel(const float* __restrict__ qf,
                              const float* __restrict__ fc,
                              const float* __restrict__ fs,
                              bf16* __restrict__ qb)
{
  int p = blockIdx.x * blockDim.x + threadIdx.x;
  int j = p & 31;
  int h = (p >> 5) & 15;
  int s = (p >> 9) & 2047;
  int b = p >> 20;
  const float* src = qf + (size_t)(b * CS + s) * CNQ + h * CHD + j * 2;
  float x0 = src[0], x1 = src[1];
  float c = fc[s * 32 + j], sn = fs[s * 32 + j];
  bf16* dst = qb + ((size_t)(b * CH + h) * CS + s) * CHD + j * 2;
  dst[0] = __float2bfloat16(x0 * c - x1 * sn);
  dst[1] = __float2bfloat16(x0 * sn + x1 * c);
}

// RoPE k from fused kv buffer: kv_f [B*S][512], k at cols 0..255.
__global__ void rope_k_kernel(const float* __restrict__ kvf,
                              const float* __restrict__ fc,
                              const float* __restrict__ fs,
                              bf16* __restrict__ kb)
{
  int p = blockIdx.x * blockDim.x + threadIdx.x;
  int j = p & 31;
  int kh = (p >> 5) & 3;
  int s = (p >> 7) & 2047;
  int b = p >> 18;
  const float* src = kvf + (size_t)(b * CS + s) * 512 + kh * CHD + j * 2;
  float x0 = src[0], x1 = src[1];
  float c = fc[s * 32 + j], sn = fs[s * 32 + j];
  bf16* dst = kb + ((size_t)(b * CKH + kh) * CS + s) * CHD + j * 2;
  dst[0] = __float2bfloat16(x0 * c - x1 * sn);
  dst[1] = __float2bfloat16(x0 * sn + x1 * c);
}

// V transpose: kv_f [B*S][512] (v at cols 256..511) -> vt [B,KH,HD,S] bf16.
__global__ __launch_bounds__(256) void transpose_v_kernel(
    const float* __restrict__ kvf, bf16* __restrict__ vt)
{
  __shared__ float T[64][65];
  const int blk = blockIdx.x;       // b*128 + kh*32 + st
  const int st = blk & 31;
  const int kh = (blk >> 5) & 3;
  const int b = blk >> 7;
  const int tid = threadIdx.x;
  const int s = tid >> 2;           // 0..63
  const int d0 = (tid & 3) * 16;
  const float* src = kvf + ((size_t)(b * CS + st * 64 + s)) * 512 + 256 + kh * CHD + d0;
  #pragma unroll
  for (int i = 0; i < 4; ++i) {
    float4 v = *(const float4*)(src + i * 4);
    T[s][d0 + i * 4 + 0] = v.x;
    T[s][d0 + i * 4 + 1] = v.y;
    T[s][d0 + i * 4 + 2] = v.z;
    T[s][d0 + i * 4 + 3] = v.w;
  }
  __syncthreads();
  const int d = tid >> 2;
  const int s0 = (tid & 3) * 16;
  unsigned short* dst = (unsigned short*)vt +
      ((size_t)((b * CKH + kh) * CHD + d)) * CS + st * 64 + s0;
  #pragma unroll
  for (int i = 0; i < 2; ++i) {
    unsigned short u[8];
    #pragma unroll
    for (int e = 0; e < 8; ++e) u[e] = f2bf(T[s0 + i * 8 + e][d]);
    *(ushort4*)(dst + i * 8 + 0) = make_ushort4(u[0], u[1], u[2], u[3]);
    *(ushort4*)(dst + i * 8 + 4) = make_ushort4(u[4], u[5], u[6], u[7]);
  }
}

// ---------------------------------------------------------------------------
// MFMA flash attention v3: ZERO barriers, no V staging.
// Block = 4 independent waves (4 q-heads of one kv group), 32 q-rows/wave.
// K frags + V^T frags straight from global (L2-resident); P per-wave via LDS.
// qt longest-first for LPT scheduling.
// ---------------------------------------------------------------------------
__global__ __launch_bounds__(256) void flash_mfma_kernel(
    const bf16* __restrict__ qb, const bf16* __restrict__ kb,
    const bf16* __restrict__ vt, bf16* __restrict__ ob)
{
  __shared__ __align__(16) unsigned short PL[4][32][40];  // per-wave P [q][k]
  const int tid = threadIdx.x;
  const int lane = tid & 63;
  const int wid = tid >> 6;
  const int l15 = lane & 15;
  const int g = lane >> 4;
  const int blk = blockIdx.x;
  const int qt = 63 - (blk & 63);     // longest-first
  const int kh = (blk >> 6) & 3;
  const int b = blk >> 8;
  const int h = kh * CREP + wid;

  const bf16* qbase = qb + ((size_t)(b * CH + h) * CS + qt * 32) * CHD;
  const bf16* kbase = kb + (size_t)(b * CKH + kh) * CS * CHD;
  const bf16* vbase = vt + (size_t)(b * CKH + kh) * CHD * CS;  // [d][s]

  bf16x8 qf[2][2];
  #pragma unroll
  for (int qs = 0; qs < 2; ++qs)
    #pragma unroll
    for (int c = 0; c < 2; ++c)
      qf[qs][c] = *(const bf16x8*)(qbase + (qs * 16 + l15) * CHD + c * 32 + g * 8);

  f32x4 oacc[2][4];
  #pragma unroll
  for (int qs = 0; qs < 2; ++qs)
    #pragma unroll
    for (int dt = 0; dt < 4; ++dt)
      oacc[qs][dt] = (f32x4){0.f, 0.f, 0.f, 0.f};
  float mrow[2] = {-1e30f, -1e30f};
  float lrow[2] = {0.f, 0.f};

  // preload K fragments for t=0
  bf16x8 kf[2][2];
  #pragma unroll
  for (int kt = 0; kt < 2; ++kt)
    #pragma unroll
    for (int c = 0; c < 2; ++c)
      kf[kt][c] = *(const bf16x8*)(kbase + (size_t)(kt * 16 + l15) * CHD + c * 32 + g * 8);

  for (int t = 0; t <= qt; ++t) {
    // V^T fragments for this tile — issued early, consumed after softmax
    bf16x8 vfr[4];
    #pragma unroll
    for (int dt = 0; dt < 4; ++dt)
      vfr[dt] = *(const bf16x8*)&vbase[(size_t)(dt * 16 + l15) * CS + t * 32 + g * 8];

    // QK^T
    f32x4 sacc[2][2];
    #pragma unroll
    for (int kt = 0; kt < 2; ++kt)
      #pragma unroll
      for (int qs = 0; qs < 2; ++qs)
        sacc[kt][qs] = (f32x4){0.f, 0.f, 0.f, 0.f};
    #pragma unroll
    for (int c = 0; c < 2; ++c)
      #pragma unroll
      for (int kt = 0; kt < 2; ++kt)
        #pragma unroll
        for (int qs = 0; qs < 2; ++qs)
          sacc[kt][qs] = __builtin_amdgcn_mfma_f32_16x16x32_bf16(kf[kt][c], qf[qs][c], sacc[kt][qs], 0, 0, 0);

    // prefetch next K tile (hides under softmax)
    if (t < qt) {
      #pragma unroll
      for (int kt = 0; kt < 2; ++kt)
        #pragma unroll
        for (int c = 0; c < 2; ++c)
          kf[kt][c] = *(const bf16x8*)(kbase + (size_t)((t + 1) * 32 + kt * 16 + l15) * CHD + c * 32 + g * 8);
    }

    // online softmax per q-set
    #pragma unroll
    for (int qs = 0; qs < 2; ++qs) {
      float s[8];
      float pm = -1e30f;
      #pragma unroll
      for (int kt = 0; kt < 2; ++kt)
        #pragma unroll
        for (int r = 0; r < 4; ++r) {
          float v = sacc[kt][qs][r] * 0.125f;
          if (t == qt) {
            int koff = kt * 16 + 4 * g + r;
            int qoff = qs * 16 + l15;
            if (koff > qoff) v = -1e30f;
          }
          s[kt * 4 + r] = v;
          pm = fmaxf(pm, v);
        }
      pm = fmaxf(pm, __shfl_xor(pm, 16, 64));
      pm = fmaxf(pm, __shfl_xor(pm, 32, 64));
      float nm = fmaxf(mrow[qs], pm);
      float corr = __expf(mrow[qs] - nm);
      mrow[qs] = nm;
      float psum = 0.f;
      unsigned short pb[8];
      #pragma unroll
      for (int i = 0; i < 8; ++i) {
        float p = __expf(s[i] - nm);
        psum += p;
        pb[i] = f2bf(p);
      }
      psum += __shfl_xor(psum, 16, 64);
      psum += __shfl_xor(psum, 32, 64);
      lrow[qs] = lrow[qs] * corr + psum;
      #pragma unroll
      for (int dt = 0; dt < 4; ++dt)
        oacc[qs][dt] *= corr;
      #pragma unroll
      for (int kt = 0; kt < 2; ++kt)
        *(ushort4*)&PL[wid][qs * 16 + l15][kt * 16 + 4 * g] =
            make_ushort4(pb[kt * 4 + 0], pb[kt * 4 + 1], pb[kt * 4 + 2], pb[kt * 4 + 3]);
    }
    // PV (same-wave LDS RAW: compiler inserts lgkmcnt wait; no barrier needed)
    #pragma unroll
    for (int qs = 0; qs < 2; ++qs) {
      bf16x8 pf = *(const bf16x8*)&PL[wid][qs * 16 + l15][g * 8];
      #pragma unroll
      for (int dt = 0; dt < 4; ++dt)
        oacc[qs][dt] = __builtin_amdgcn_mfma_f32_16x16x32_bf16(vfr[dt], pf, oacc[qs][dt], 0, 0, 0);
    }
  }

  #pragma unroll
  for (int qs = 0; qs < 2; ++qs) {
    float inv = 1.0f / lrow[qs];
    int qg = qt * 32 + qs * 16 + l15;
    unsigned short* orow = (unsigned short*)ob + (size_t)(b * CS + qg) * CNQ + h * CHD;
    #pragma unroll
    for (int dt = 0; dt < 4; ++dt) {
      *(ushort4*)&orow[dt * 16 + 4 * g] =
          make_ushort4(f2bf(oacc[qs][dt][0] * inv), f2bf(oacc[qs][dt][1] * inv),
                       f2bf(oacc[qs][dt][2] * inv), f2bf(oacc[qs][dt][3] * inv));
    }
  }
}

// ---------------------------------------------------------------------------
extern "C" void kernel_launch(void* const* d_in, const int* in_sizes, int n_in,
                              void* d_out, int out_size, void* d_ws, size_t ws_size,
                              hipStream_t stream)
{
  const float* x  = (const float*)d_in[0];
  const float* wq = (const float*)d_in[1];
  const float* wk = (const float*)d_in[2];
  const float* wv = (const float*)d_in[3];
  const float* wo = (const float*)d_in[4];
  const float* fc = (const float*)d_in[5];
  const float* fs = (const float*)d_in[6];
  float* out = (float*)d_out;

  char* ws = (char*)d_ws;
  // live-range-packed workspace:
  bf16*  x_b  = (bf16*)(ws);                 // [0,8M)     dead after kv-GEMM
  float* q_f  = (float*)(ws + 8388608);      // [8M,16M)   dead after rope_q
  float* kv_f = (float*)(ws + 25165824);     // [24M,32M)  fused k|v, dead after rope_k/transpose_v
  bf16*  wqt  = (bf16*)(ws + 33554432);      // 2MB
  bf16*  wkvt = (bf16*)(ws + 35651584);      // 1MB  (rows 0..255 = wk^T, 256..511 = wv^T)
  bf16*  q_b  = (bf16*)(ws);                 // reuse x_b after kv-GEMM
  bf16*  k_b  = (bf16*)(ws + 8388608);       // reuse q_f
  bf16*  v_t  = (bf16*)(ws + 10485760);      // 2MB, V^T [B,KH,HD,S]
  bf16*  o_b  = (bf16*)(ws + 12582912);      // 8MB
  bf16*  wot  = (bf16*)(ws + 25165824);      // reuse kv_f region

  conv_x_kernel<<<2048, 256, 0, stream>>>(x, x_b);
  transpose_conv_kernel<<<dim3(16, 16), 256, 0, stream>>>(wq, wqt, CD, CNQ);
  transpose_conv_kernel<<<dim3(16, 4), 256, 0, stream>>>(wk, wkvt, CD, CNKV);
  transpose_conv_kernel<<<dim3(16, 4), 256, 0, stream>>>(wv, wkvt + 256 * CD, CD, CNKV);
  gemm_mfma_kernel<<<dim3(64, 8), 256, 0, stream>>>(x_b, wqt, q_f, CM, CNQ, CD);
  gemm_mfma_kernel<<<dim3(64, 4), 256, 0, stream>>>(x_b, wkvt, kv_f, CM, 512, CD);
  rope_q_kernel<<<(CB * CS * CH * 32) / 256, 256, 0, stream>>>(q_f, fc, fs, q_b);
  rope_k_kernel<<<(CB * CS * CKH * 32) / 256, 256, 0, stream>>>(kv_f, fc, fs, k_b);
  transpose_v_kernel<<<CB * CKH * 32, 256, 0, stream>>>(kv_f, v_t);
  transpose_conv_kernel<<<dim3(16, 16), 256, 0, stream>>>(wo, wot, CNQ, CD);
  flash_mfma_kernel<<<CB * CKH * (CS / 32), 256, 0, stream>>>(q_b, k_b, v_t, o_b);
  gemm_mfma_kernel<<<dim3(64, 8), 256, 0, stream>>>(o_b, wot, out, CM, CD, CNQ);
}